// Round 2
// baseline (435.321 us; speedup 1.0000x reference)
//
#include <hip/hip_runtime.h>
#include <stdint.h>

#define N_ROWS 65536
#define N_CLS  1000
#define KPAD   1024
#define FEAT   256
#define MT     64          // rows per block
#define BK     64          // k per iteration
#define NIT    (KPAD/BK)   // 16
#define LDA    72          // padded LDS stride for A (bf16): 144 B -> 2-way bank alias only (free)

typedef short bf16x8 __attribute__((ext_vector_type(8)));
typedef float f32x4  __attribute__((ext_vector_type(4)));

__device__ __forceinline__ ushort f32_to_bf16_rne(float f) {
    union { float f; uint32_t u; } x; x.f = f;
    uint32_t u = x.u + 0x7FFFu + ((x.u >> 16) & 1u);
    return (ushort)(u >> 16);
}

// Prep: store centers as bf16 in EXACT MFMA B-fragment order:
//   Bfrag[it][ks][w][nt][lane][j]  (it=k/64, ks=(k/32)&1, quad=(k/8)&3, j=k&7,
//                                   w=n/64, nt=(n/16)&3, ml=n&15, lane=quad*16+ml)
// so each wave's fragment load in main is ONE coalesced 1 KB dwordx4 burst.
// Also csq[c] = ||centers[c]||^2 (zero-padded to KPAD); zero d_out.
__global__ __launch_bounds__(256) void prep_kernel(const float* __restrict__ centers,
                                                   ushort* __restrict__ Bfrag,
                                                   float* __restrict__ csq,
                                                   float* __restrict__ out) {
    const int c = blockIdx.x;     // k index 0..1023
    const int n = threadIdx.x;    // n index 0..255
    float v = 0.f;
    if (c < N_CLS) v = centers[(size_t)c * FEAT + n];

    const int it   = c >> 6;
    const int ks   = (c >> 5) & 1;
    const int quad = (c >> 3) & 3;
    const int j    = c & 7;
    const int w    = n >> 6;
    const int nt   = (n >> 4) & 3;
    const int ml   = n & 15;
    const int lane = quad * 16 + ml;
    const size_t idx = ((size_t)(((it * 2 + ks) * 4 + w) * 4 + nt) * 64 + lane) * 8 + j;
    Bfrag[idx] = f32_to_bf16_rne(v);

    float sq = v * v;
    #pragma unroll
    for (int off = 32; off > 0; off >>= 1) sq += __shfl_down(sq, off);
    __shared__ float red[4];
    if ((threadIdx.x & 63) == 0) red[threadIdx.x >> 6] = sq;
    __syncthreads();
    if (threadIdx.x == 0) {
        csq[c] = red[0] + red[1] + red[2] + red[3];
        if (c == 0) out[0] = 0.f;
    }
}

// Single-barrier pipelined main loop:
//  - A (gt mask, bf16) double-buffered in LDS; gt loads for it+1 prefetched and
//    left in flight across the MFMA phase (B loads issued first -> compiler
//    waits vmcnt(4), not 0, before MFMA).
//  - B fragments read directly from L2-resident Bfrag in fragment order:
//    64 lanes x 16 B = 1 KB contiguous per load instruction. No LDS for B.
//  - gt in {0,1}: mask pack = (v0 + v1<<16)*0x3F80; integer row-count.
__global__ __launch_bounds__(256, 4) void main_kernel(const int* __restrict__ gt,
                                                      const float* __restrict__ features,
                                                      const ushort* __restrict__ Bfrag,
                                                      const float* __restrict__ csq,
                                                      float* __restrict__ out) {
    __shared__ ushort As[2 * MT * LDA];   // 18432 B (double-buffered A tile)
    __shared__ float  rcS[256];
    __shared__ float  t2S[256];
    __shared__ float  rowcnt[MT];
    __shared__ float  t2row[MT];
    __shared__ float  blockred[4];

    const int tid  = threadIdx.x;
    const int m0   = blockIdx.x * MT;
    const int r    = tid >> 2;       // staging row 0..63
    const int kc   = tid & 3;        // staging k-quarter
    const int lane = tid & 63;
    const int w    = tid >> 6;       // wave 0..3 -> cols w*64
    const int ml   = lane & 15;
    const int quad = lane >> 4;

    f32x4 acc[4][4];
    #pragma unroll
    for (int i = 0; i < 4; i++)
        #pragma unroll
        for (int j = 0; j < 4; j++)
            #pragma unroll
            for (int k = 0; k < 4; k++) acc[i][j][k] = 0.f;

    int   rci = 0;
    float t2  = 0.f;
    const int* gtrow = gt + (size_t)(m0 + r) * N_CLS;

    auto load_gt = [&](int it, int (&vv)[16]) {
        const int kb = it * BK + kc * 16;
        if (kb + 16 <= N_CLS) {
            const int4* p = (const int4*)(gtrow + kb);
            int4 a0 = p[0], a1 = p[1], a2 = p[2], a3 = p[3];
            vv[0]=a0.x;  vv[1]=a0.y;  vv[2]=a0.z;  vv[3]=a0.w;
            vv[4]=a1.x;  vv[5]=a1.y;  vv[6]=a1.z;  vv[7]=a1.w;
            vv[8]=a2.x;  vv[9]=a2.y;  vv[10]=a2.z; vv[11]=a2.w;
            vv[12]=a3.x; vv[13]=a3.y; vv[14]=a3.z; vv[15]=a3.w;
        } else {
            #pragma unroll
            for (int j = 0; j < 16; j++) {
                int k = kb + j;
                vv[j] = (k < N_CLS) ? gtrow[k] : 0;
            }
        }
    };

    auto convert_store = [&](int buf, int it, const int (&vv)[16]) {
        const int kb = it * BK + kc * 16;
        const float4* cp = (const float4*)(csq + kb);   // zero-padded to KPAD
        float4 q0 = cp[0], q1 = cp[1], q2 = cp[2], q3 = cp[3];
        float cs[16] = {q0.x,q0.y,q0.z,q0.w, q1.x,q1.y,q1.z,q1.w,
                        q2.x,q2.y,q2.z,q2.w, q3.x,q3.y,q3.z,q3.w};
        uint32_t u[8];
        #pragma unroll
        for (int j = 0; j < 8; j++)   // v in {0,1}: (v0 + v1<<16)*0x3F80 packs 2x bf16(1.0)
            u[j] = (uint32_t)(vv[2*j] + (vv[2*j+1] << 16)) * 0x3F80u;
        #pragma unroll
        for (int j = 0; j < 16; j++) {
            rci += vv[j];                      // integer row-count
            t2  += (float)vv[j] * cs[j];       // exact: 1.0*cs or 0
        }
        uint4* dst = (uint4*)&As[buf * (MT * LDA) + r * LDA + kc * 16];
        dst[0] = make_uint4(u[0], u[1], u[2], u[3]);
        dst[1] = make_uint4(u[4], u[5], u[6], u[7]);
    };

    // ---- prologue: stage A for it=0 ----
    {
        int v0[16];
        load_gt(0, v0);
        convert_store(0, 0, v0);
    }
    __syncthreads();

    int cur = 0;
    // per-wave fragment base: Bfrag[it][ks][w][nt][lane][8]
    const ushort* bbase = Bfrag + ((size_t)w * 4) * 64 * 8 + (size_t)lane * 8;

    for (int it = 0; it < NIT; ++it) {
        const bool hn = (it + 1 < NIT);

        // ---- B fragments: coalesced 1 KB bursts from L2-resident table (issue FIRST) ----
        bf16x8 b0[4], b1[4];
        {
            const ushort* p0 = bbase + (size_t)(it * 2 + 0) * (4 * 4 * 64 * 8);
            const ushort* p1 = bbase + (size_t)(it * 2 + 1) * (4 * 4 * 64 * 8);
            #pragma unroll
            for (int nt = 0; nt < 4; ++nt) b0[nt] = *(const bf16x8*)(p0 + nt * 64 * 8);
            #pragma unroll
            for (int nt = 0; nt < 4; ++nt) b1[nt] = *(const bf16x8*)(p1 + nt * 64 * 8);
        }

        // ---- prefetch gt for it+1; stays in flight across the MFMA phase ----
        int vn[16];
        if (hn) load_gt(it + 1, vn);

        // ---- MFMA: A from LDS, B from regs ----
        const ushort* Ab = &As[cur * (MT * LDA)];
        #pragma unroll
        for (int ks = 0; ks < 2; ++ks) {
            const int kk = ks * 32 + quad * 8;
            bf16x8 af[4];
            #pragma unroll
            for (int mt = 0; mt < 4; mt++)
                af[mt] = *(const bf16x8*)&Ab[(mt * 16 + ml) * LDA + kk];
            #pragma unroll
            for (int mt = 0; mt < 4; mt++)
                #pragma unroll
                for (int nt = 0; nt < 4; nt++)
                    acc[mt][nt] = __builtin_amdgcn_mfma_f32_16x16x32_bf16(
                        af[mt], ks ? b1[nt] : b0[nt], acc[mt][nt], 0, 0, 0);
        }

        // ---- write next A tile into the other buffer ----
        if (hn) convert_store(cur ^ 1, it + 1, vn);
        __syncthreads();            // single barrier per iteration
        cur ^= 1;
    }

    // ---- per-row reductions (rowcnt, t2row) ----
    rcS[tid] = (float)rci;
    t2S[tid] = t2;
    __syncthreads();
    if (tid < MT) {
        rowcnt[tid] = rcS[tid*4] + rcS[tid*4+1] + rcS[tid*4+2] + rcS[tid*4+3];
        t2row[tid]  = t2S[tid*4] + t2S[tid*4+1] + t2S[tid*4+2] + t2S[tid*4+3];
    }
    __syncthreads();

    // ---- epilogue: read features once, fold all three terms ----
    float part = 0.f;
    #pragma unroll
    for (int mt = 0; mt < 4; mt++) {
        #pragma unroll
        for (int nt = 0; nt < 4; nt++) {
            const int n = w * 64 + nt * 16 + ml;
            #pragma unroll
            for (int reg = 0; reg < 4; reg++) {
                const int ri = mt * 16 + quad * 4 + reg;
                const float f = features[(size_t)(m0 + ri) * FEAT + n];
                const float T = acc[mt][nt][reg];
                part += f * (rowcnt[ri] * f - 2.f * T) + t2row[ri] * (1.f / 256.f);
            }
        }
    }
    #pragma unroll
    for (int off = 32; off > 0; off >>= 1) part += __shfl_down(part, off);
    if (lane == 0) blockred[w] = part;
    __syncthreads();
    if (tid == 0)
        atomicAdd(out, (blockred[0] + blockred[1] + blockred[2] + blockred[3]) *
                           (1.f / (float)N_ROWS));
}

extern "C" void kernel_launch(void* const* d_in, const int* in_sizes, int n_in,
                              void* d_out, int out_size, void* d_ws, size_t ws_size,
                              hipStream_t stream) {
    const int*   gt       = (const int*)d_in[0];
    const float* features = (const float*)d_in[1];
    const float* centers  = (const float*)d_in[2];
    float*       out      = (float*)d_out;

    ushort* Bfrag = (ushort*)d_ws;                                    // 256*1024*2 = 512 KB
    float*  csq   = (float*)((char*)d_ws + (size_t)FEAT * KPAD * 2);  // 4 KB

    prep_kernel<<<KPAD, 256, 0, stream>>>(centers, Bfrag, csq, out);
    main_kernel<<<N_ROWS / MT, 256, 0, stream>>>(gt, features, Bfrag, csq, out);
}

// Round 3
// 423.097 us; speedup vs baseline: 1.0289x; 1.0289x over previous
//
#include <hip/hip_runtime.h>
#include <stdint.h>

#define N_ROWS 65536
#define N_CLS  1000
#define KPAD   1024
#define FEAT   256
#define MT     64          // rows per block
#define BK     64          // k per iteration
#define NIT    (KPAD/BK)   // 16

typedef short bf16x8 __attribute__((ext_vector_type(8)));
typedef float f32x4  __attribute__((ext_vector_type(4)));

__device__ __forceinline__ ushort f32_to_bf16_rne(float f) {
    union { float f; uint32_t u; } x; x.f = f;
    uint32_t u = x.u + 0x7FFFu + ((x.u >> 16) & 1u);
    return (ushort)(u >> 16);
}

// Prep: store centers as bf16 in EXACT MFMA B-fragment order:
//   Bfrag[it][ks][w][nt][lane][j]  (k = it*64+ks*32+quad*8+j, lane=quad*16+ml,
//                                   n = w*64+nt*16+ml)
// so each wave's fragment load in main is ONE coalesced 1 KB dwordx4 burst.
// Also csq[c] = ||centers[c]||^2 (zero-padded to KPAD); zero d_out.
__global__ __launch_bounds__(256) void prep_kernel(const float* __restrict__ centers,
                                                   ushort* __restrict__ Bfrag,
                                                   float* __restrict__ csq,
                                                   float* __restrict__ out) {
    const int c = blockIdx.x;     // k index 0..1023
    const int n = threadIdx.x;    // n index 0..255
    float v = 0.f;
    if (c < N_CLS) v = centers[(size_t)c * FEAT + n];

    const int it   = c >> 6;
    const int ks   = (c >> 5) & 1;
    const int quad = (c >> 3) & 3;
    const int j    = c & 7;
    const int w    = n >> 6;
    const int nt   = (n >> 4) & 3;
    const int ml   = n & 15;
    const int lane = quad * 16 + ml;
    const size_t idx = ((size_t)(((it * 2 + ks) * 4 + w) * 4 + nt) * 64 + lane) * 8 + j;
    Bfrag[idx] = f32_to_bf16_rne(v);

    float sq = v * v;
    #pragma unroll
    for (int off = 32; off > 0; off >>= 1) sq += __shfl_down(sq, off);
    __shared__ float red[4];
    if ((threadIdx.x & 63) == 0) red[threadIdx.x >> 6] = sq;
    __syncthreads();
    if (threadIdx.x == 0) {
        csq[c] = red[0] + red[1] + red[2] + red[3];
        if (c == 0) out[0] = 0.f;
    }
}

// Single-barrier pipelined main loop.
//  - A (gt mask, bf16) double-buffered in LDS, stored in MFMA FRAGMENT ORDER
//    As[buf][ks][mt][slot][8] with a 3-bit XOR swizzle on the slot index:
//    slot = (ks*4+mt)*64 + quad*16+ml, then slot ^= (ml>>3)|(ks<<1)|((quad>>1)<<2).
//    Reads: contiguous 1 KB ds_read_b128 per (ks,mt) -> conflict-free.
//    Writes: swizzle spreads each 16-lane quarter over all 8 bank groups -> free.
//  - B fragments read directly from L2-resident Bfrag (1 KB coalesced bursts).
//  - gt loads for it+1 issued BEFORE the MFMA phase (vmcnt leaves them in
//    flight: MFMA only waits on the 8 B-loads issued earlier).
//  - gt in {0,1}: mask pack = (v0 + v1<<16)*0x3F80; integer row-count.
__global__ __launch_bounds__(256, 3) void main_kernel(const int* __restrict__ gt,
                                                      const float* __restrict__ features,
                                                      const ushort* __restrict__ Bfrag,
                                                      const float* __restrict__ csq,
                                                      float* __restrict__ out) {
    __shared__ ushort As[2 * 2 * 4 * 64 * 8];   // 16 KB: [buf][ks][mt][slot][j]
    __shared__ float  rcS[256];
    __shared__ float  t2S[256];
    __shared__ float  rowcnt[MT];
    __shared__ float  t2row[MT];
    __shared__ float  blockred[4];

    const int tid  = threadIdx.x;
    const int m0   = blockIdx.x * MT;
    const int r    = tid >> 2;       // staging row 0..63
    const int kc   = tid & 3;        // staging k-quarter (16 k's)
    const int lane = tid & 63;
    const int w    = tid >> 6;       // wave 0..3 -> cols w*64
    const int ml   = lane & 15;
    const int quad = lane >> 4;

    f32x4 acc[4][4];
    #pragma unroll
    for (int i = 0; i < 4; i++)
        #pragma unroll
        for (int j = 0; j < 4; j++)
            #pragma unroll
            for (int k = 0; k < 4; k++) acc[i][j][k] = 0.f;

    int   rci = 0;
    float t2  = 0.f;
    const int* gtrow = gt + (size_t)(m0 + r) * N_CLS;

    // ---- precomputed swizzled LDS write addresses (thread-constant) ----
    // thread (r,kc) writes row r, k-local kc*16..+15 -> two 16B slots:
    //   slot0: ks=kc>>1, quad=(kc&1)*2,   slot1: quad=(kc&1)*2+1
    const int mt_w = r >> 4, ml_w = r & 15;
    const int ks_w = kc >> 1, qb = (kc & 1) * 2;
    const int xw   = (ml_w >> 3) | (ks_w << 1) | ((kc & 1) << 2); // (quad>>1)==kc&1 for both slots
    const int slot0 = (((ks_w * 4 + mt_w) * 64) + (qb * 16 + ml_w)) ^ xw;
    const int slot1 = (((ks_w * 4 + mt_w) * 64) + ((qb + 1) * 16 + ml_w)) ^ xw;
    ushort* const wptr0 = As + slot0 * 8;   // + buf*4096 elements
    ushort* const wptr1 = As + slot1 * 8;

    // ---- precomputed swizzled LDS read lane-offsets (elements) ----
    const int xr0 = ((lane >> 3) & 1) | (0 << 1) | (((lane >> 5) & 1) << 2);
    const int lx0 = (lane ^ xr0) * 8;          // ks = 0
    const int lx1 = (lane ^ (xr0 | 2)) * 8;    // ks = 1

    auto load_gt = [&](int it, int (&vv)[16]) {
        const int kb = it * BK + kc * 16;
        if (kb + 16 <= N_CLS) {
            const int4* p = (const int4*)(gtrow + kb);
            int4 a0 = p[0], a1 = p[1], a2 = p[2], a3 = p[3];
            vv[0]=a0.x;  vv[1]=a0.y;  vv[2]=a0.z;  vv[3]=a0.w;
            vv[4]=a1.x;  vv[5]=a1.y;  vv[6]=a1.z;  vv[7]=a1.w;
            vv[8]=a2.x;  vv[9]=a2.y;  vv[10]=a2.z; vv[11]=a2.w;
            vv[12]=a3.x; vv[13]=a3.y; vv[14]=a3.z; vv[15]=a3.w;
        } else {
            #pragma unroll
            for (int j = 0; j < 16; j++) {
                int k = kb + j;
                vv[j] = (k < N_CLS) ? gtrow[k] : 0;
            }
        }
    };

    auto convert_store = [&](int buf, int it, const int (&vv)[16]) {
        const int kb = it * BK + kc * 16;
        const float4* cp = (const float4*)(csq + kb);   // zero-padded to KPAD, L1-hot
        float4 q0 = cp[0], q1 = cp[1], q2 = cp[2], q3 = cp[3];
        float cs[16] = {q0.x,q0.y,q0.z,q0.w, q1.x,q1.y,q1.z,q1.w,
                        q2.x,q2.y,q2.z,q2.w, q3.x,q3.y,q3.z,q3.w};
        uint32_t u[8];
        #pragma unroll
        for (int j = 0; j < 8; j++)   // v in {0,1}: (v0 + v1<<16)*0x3F80 packs 2x bf16(1.0)
            u[j] = (uint32_t)(vv[2*j] + (vv[2*j+1] << 16)) * 0x3F80u;
        #pragma unroll
        for (int j = 0; j < 16; j++) {
            rci += vv[j];                      // integer row-count
            t2  += (float)vv[j] * cs[j];       // exact: 1.0*cs or 0
        }
        uint4* d0 = (uint4*)(wptr0 + buf * 4096);
        uint4* d1 = (uint4*)(wptr1 + buf * 4096);
        *d0 = make_uint4(u[0], u[1], u[2], u[3]);
        *d1 = make_uint4(u[4], u[5], u[6], u[7]);
    };

    // ---- prologue: stage A for it=0 ----
    {
        int v0[16];
        load_gt(0, v0);
        convert_store(0, 0, v0);
    }
    __syncthreads();

    int cur = 0;
    // per-wave fragment base: Bfrag[it][ks][w][nt][lane][8]
    const ushort* bbase = Bfrag + ((size_t)w * 4) * 64 * 8 + (size_t)lane * 8;

    for (int it = 0; it < NIT; ++it) {
        const bool hn = (it + 1 < NIT);

        // ---- B fragments: coalesced 1 KB bursts from L2-resident table (FIRST) ----
        bf16x8 b0[4], b1[4];
        {
            const ushort* p0 = bbase + (size_t)(it * 2 + 0) * (4 * 4 * 64 * 8);
            const ushort* p1 = bbase + (size_t)(it * 2 + 1) * (4 * 4 * 64 * 8);
            #pragma unroll
            for (int nt = 0; nt < 4; ++nt) b0[nt] = *(const bf16x8*)(p0 + nt * 64 * 8);
            #pragma unroll
            for (int nt = 0; nt < 4; ++nt) b1[nt] = *(const bf16x8*)(p1 + nt * 64 * 8);
        }

        // ---- prefetch gt for it+1; stays in flight across the MFMA phase ----
        int vn[16];
        if (hn) load_gt(it + 1, vn);

        // ---- MFMA: A from LDS fragment slots (contiguous reads), B from regs ----
        #pragma unroll
        for (int ks = 0; ks < 2; ++ks) {
            const int lx = ks ? lx1 : lx0;
            bf16x8 af[4];
            #pragma unroll
            for (int mt = 0; mt < 4; mt++)
                af[mt] = *(const bf16x8*)(As + cur * 4096 + (ks * 4 + mt) * 512 + lx);
            #pragma unroll
            for (int mt = 0; mt < 4; mt++)
                #pragma unroll
                for (int nt = 0; nt < 4; nt++)
                    acc[mt][nt] = __builtin_amdgcn_mfma_f32_16x16x32_bf16(
                        af[mt], ks ? b1[nt] : b0[nt], acc[mt][nt], 0, 0, 0);
        }

        // ---- write next A tile into the other buffer ----
        if (hn) convert_store(cur ^ 1, it + 1, vn);
        __syncthreads();            // single barrier per iteration
        cur ^= 1;
    }

    // ---- per-row reductions (rowcnt, t2row) ----
    rcS[tid] = (float)rci;
    t2S[tid] = t2;
    __syncthreads();
    if (tid < MT) {
        rowcnt[tid] = rcS[tid*4] + rcS[tid*4+1] + rcS[tid*4+2] + rcS[tid*4+3];
        t2row[tid]  = t2S[tid*4] + t2S[tid*4+1] + t2S[tid*4+2] + t2S[tid*4+3];
    }
    __syncthreads();

    // ---- epilogue: read features once, fold all three terms ----
    float part = 0.f;
    #pragma unroll
    for (int mt = 0; mt < 4; mt++) {
        #pragma unroll
        for (int nt = 0; nt < 4; nt++) {
            const int n = w * 64 + nt * 16 + ml;
            #pragma unroll
            for (int reg = 0; reg < 4; reg++) {
                const int ri = mt * 16 + quad * 4 + reg;
                const float f = features[(size_t)(m0 + ri) * FEAT + n];
                const float T = acc[mt][nt][reg];
                part += f * (rowcnt[ri] * f - 2.f * T) + t2row[ri] * (1.f / 256.f);
            }
        }
    }
    #pragma unroll
    for (int off = 32; off > 0; off >>= 1) part += __shfl_down(part, off);
    if (lane == 0) blockred[w] = part;
    __syncthreads();
    if (tid == 0)
        atomicAdd(out, (blockred[0] + blockred[1] + blockred[2] + blockred[3]) *
                           (1.f / (float)N_ROWS));
}

extern "C" void kernel_launch(void* const* d_in, const int* in_sizes, int n_in,
                              void* d_out, int out_size, void* d_ws, size_t ws_size,
                              hipStream_t stream) {
    const int*   gt       = (const int*)d_in[0];
    const float* features = (const float*)d_in[1];
    const float* centers  = (const float*)d_in[2];
    float*       out      = (float*)d_out;

    ushort* Bfrag = (ushort*)d_ws;                                    // 256*1024*2 = 512 KB
    float*  csq   = (float*)((char*)d_ws + (size_t)FEAT * KPAD * 2);  // 4 KB

    prep_kernel<<<KPAD, 256, 0, stream>>>(centers, Bfrag, csq, out);
    main_kernel<<<N_ROWS / MT, 256, 0, stream>>>(gt, features, Bfrag, csq, out);
}

// Round 4
// 420.614 us; speedup vs baseline: 1.0350x; 1.0059x over previous
//
#include <hip/hip_runtime.h>
#include <stdint.h>

#define N_ROWS 65536
#define N_CLS  1000
#define KPAD   1024
#define FEAT   256
#define MT     64          // rows per block
#define BK     64          // k per iteration
#define NIT    (KPAD/BK)   // 16

typedef short bf16x8 __attribute__((ext_vector_type(8)));
typedef float f32x4  __attribute__((ext_vector_type(4)));

__device__ __forceinline__ ushort f32_to_bf16_rne(float f) {
    union { float f; uint32_t u; } x; x.f = f;
    uint32_t u = x.u + 0x7FFFu + ((x.u >> 16) & 1u);
    return (ushort)(u >> 16);
}

// Prep: store centers as bf16 in EXACT MFMA B-fragment order:
//   Bfrag[it][ks][w][nt][lane][j]  (k = it*64+ks*32+quad*8+j, lane=quad*16+ml,
//                                   n = w*64+nt*16+ml)
// so each wave's fragment load in main is ONE coalesced 1 KB dwordx4 burst.
// Also csq[c] = ||centers[c]||^2 (zero-padded to KPAD); zero d_out.
__global__ __launch_bounds__(256) void prep_kernel(const float* __restrict__ centers,
                                                   ushort* __restrict__ Bfrag,
                                                   float* __restrict__ csq,
                                                   float* __restrict__ out) {
    const int c = blockIdx.x;     // k index 0..1023
    const int n = threadIdx.x;    // n index 0..255
    float v = 0.f;
    if (c < N_CLS) v = centers[(size_t)c * FEAT + n];

    const int it   = c >> 6;
    const int ks   = (c >> 5) & 1;
    const int quad = (c >> 3) & 3;
    const int j    = c & 7;
    const int w    = n >> 6;
    const int nt   = (n >> 4) & 3;
    const int ml   = n & 15;
    const int lane = quad * 16 + ml;
    const size_t idx = ((size_t)(((it * 2 + ks) * 4 + w) * 4 + nt) * 64 + lane) * 8 + j;
    Bfrag[idx] = f32_to_bf16_rne(v);

    float sq = v * v;
    #pragma unroll
    for (int off = 32; off > 0; off >>= 1) sq += __shfl_down(sq, off);
    __shared__ float red[4];
    if ((threadIdx.x & 63) == 0) red[threadIdx.x >> 6] = sq;
    __syncthreads();
    if (threadIdx.x == 0) {
        csq[c] = red[0] + red[1] + red[2] + red[3];
        if (c == 0) out[0] = 0.f;
    }
}

// Single-barrier pipelined main loop, gt prefetch depth = 2:
//  - A (gt mask, bf16) double-buffered in LDS in MFMA fragment order with a
//    3-bit XOR swizzle (reads AND writes conflict-free).
//  - B fragments read directly from L2-resident Bfrag (1 KB coalesced bursts).
//  - gt(it+2) issued at top of iter it, consumed by convert at END of iter
//    it+1 -> ~1.8 iterations of HBM-latency cover (was ~0.7).  Two named
//    register buffers + unroll-2 loop keep all indexing compile-time.
//  - csq staged once in LDS (4 KB, broadcast reads) so the convert tail has
//    no global-load dependency.
//  - gt in {0,1}: mask pack = (v0 + v1<<16)*0x3F80; integer row-count.
__global__ __launch_bounds__(256, 3) void main_kernel(const int* __restrict__ gt,
                                                      const float* __restrict__ features,
                                                      const ushort* __restrict__ Bfrag,
                                                      const float* __restrict__ csq,
                                                      float* __restrict__ out) {
    __shared__ ushort As[2 * 2 * 4 * 64 * 8];   // 16 KB: [buf][ks][mt][slot][j]
    __shared__ float  csqS[KPAD];               // 4 KB
    __shared__ float  rcS[256];
    __shared__ float  t2S[256];
    __shared__ float  rowcnt[MT];
    __shared__ float  t2row[MT];
    __shared__ float  blockred[4];

    const int tid  = threadIdx.x;
    const int m0   = blockIdx.x * MT;
    const int r    = tid >> 2;       // staging row 0..63
    const int kc   = tid & 3;        // staging k-quarter (16 k's)
    const int lane = tid & 63;
    const int w    = tid >> 6;       // wave 0..3 -> cols w*64
    const int ml   = lane & 15;
    const int quad = lane >> 4;

    f32x4 acc[4][4];
    #pragma unroll
    for (int i = 0; i < 4; i++)
        #pragma unroll
        for (int j = 0; j < 4; j++)
            #pragma unroll
            for (int k = 0; k < 4; k++) acc[i][j][k] = 0.f;

    int   rci = 0;
    float t2  = 0.f;
    const int* gtrow = gt + (size_t)(m0 + r) * N_CLS;

    // ---- precomputed swizzled LDS write addresses (thread-constant) ----
    const int mt_w = r >> 4, ml_w = r & 15;
    const int ks_w = kc >> 1, qb = (kc & 1) * 2;
    const int xw   = (ml_w >> 3) | (ks_w << 1) | ((kc & 1) << 2);
    const int slot0 = (((ks_w * 4 + mt_w) * 64) + (qb * 16 + ml_w)) ^ xw;
    const int slot1 = (((ks_w * 4 + mt_w) * 64) + ((qb + 1) * 16 + ml_w)) ^ xw;
    ushort* const wptr0 = As + slot0 * 8;   // + buf*4096 elements
    ushort* const wptr1 = As + slot1 * 8;

    // ---- precomputed swizzled LDS read lane-offsets (elements) ----
    const int xr0 = ((lane >> 3) & 1) | (((lane >> 5) & 1) << 2);
    const int lx0 = (lane ^ xr0) * 8;          // ks = 0
    const int lx1 = (lane ^ (xr0 | 2)) * 8;    // ks = 1

    auto load_gt = [&](int it, int (&vv)[16]) {
        const int kb = it * BK + kc * 16;
        if (kb + 16 <= N_CLS) {
            const int4* p = (const int4*)(gtrow + kb);
            int4 a0 = p[0], a1 = p[1], a2 = p[2], a3 = p[3];
            vv[0]=a0.x;  vv[1]=a0.y;  vv[2]=a0.z;  vv[3]=a0.w;
            vv[4]=a1.x;  vv[5]=a1.y;  vv[6]=a1.z;  vv[7]=a1.w;
            vv[8]=a2.x;  vv[9]=a2.y;  vv[10]=a2.z; vv[11]=a2.w;
            vv[12]=a3.x; vv[13]=a3.y; vv[14]=a3.z; vv[15]=a3.w;
        } else {
            #pragma unroll
            for (int j = 0; j < 16; j++) {
                int k = kb + j;
                vv[j] = (k < N_CLS) ? gtrow[k] : 0;
            }
        }
    };

    auto convert_store = [&](int buf, int it, const int (&vv)[16]) {
        const int kb = it * BK + kc * 16;
        const float4* cp = (const float4*)&csqS[kb];   // LDS, 16-lane broadcast
        float4 q0 = cp[0], q1 = cp[1], q2 = cp[2], q3 = cp[3];
        float cs[16] = {q0.x,q0.y,q0.z,q0.w, q1.x,q1.y,q1.z,q1.w,
                        q2.x,q2.y,q2.z,q2.w, q3.x,q3.y,q3.z,q3.w};
        uint32_t u[8];
        #pragma unroll
        for (int j = 0; j < 8; j++)   // v in {0,1}: (v0 + v1<<16)*0x3F80 packs 2x bf16(1.0)
            u[j] = (uint32_t)(vv[2*j] + (vv[2*j+1] << 16)) * 0x3F80u;
        #pragma unroll
        for (int j = 0; j < 16; j++) {
            rci += vv[j];                      // integer row-count
            t2  += (float)vv[j] * cs[j];       // exact: 1.0*cs or 0
        }
        uint4* d0 = (uint4*)(wptr0 + buf * 4096);
        uint4* d1 = (uint4*)(wptr1 + buf * 4096);
        *d0 = make_uint4(u[0], u[1], u[2], u[3]);
        *d1 = make_uint4(u[4], u[5], u[6], u[7]);
    };

    // per-wave fragment base: Bfrag[it][ks][w][nt][lane][8]
    const ushort* bbase = Bfrag + ((size_t)w * 4) * 64 * 8 + (size_t)lane * 8;

    auto mfma_iter = [&](int buf, int it) {
        bf16x8 b0[4], b1[4];
        const ushort* p0 = bbase + (size_t)(it * 2 + 0) * (4 * 4 * 64 * 8);
        const ushort* p1 = bbase + (size_t)(it * 2 + 1) * (4 * 4 * 64 * 8);
        #pragma unroll
        for (int nt = 0; nt < 4; ++nt) b0[nt] = *(const bf16x8*)(p0 + nt * 64 * 8);
        #pragma unroll
        for (int nt = 0; nt < 4; ++nt) b1[nt] = *(const bf16x8*)(p1 + nt * 64 * 8);
        #pragma unroll
        for (int ks = 0; ks < 2; ++ks) {
            const int lx = ks ? lx1 : lx0;
            bf16x8 af[4];
            #pragma unroll
            for (int mt = 0; mt < 4; mt++)
                af[mt] = *(const bf16x8*)(As + buf * 4096 + (ks * 4 + mt) * 512 + lx);
            #pragma unroll
            for (int mt = 0; mt < 4; mt++)
                #pragma unroll
                for (int nt = 0; nt < 4; nt++)
                    acc[mt][nt] = __builtin_amdgcn_mfma_f32_16x16x32_bf16(
                        af[mt], ks ? b1[nt] : b0[nt], acc[mt][nt], 0, 0, 0);
        }
    };

    // ---- prologue ----
    int gtA[16], gtB[16];
    {
        // stage csq -> LDS (one float4 per thread)
        *(float4*)&csqS[tid * 4] = *(const float4*)&csq[tid * 4];
        load_gt(0, gtA);
        __syncthreads();              // csqS visible
        convert_store(0, 0, gtA);     // A(0)
        load_gt(1, gtA);              // gt(1) in flight
        __syncthreads();              // A(0) visible
    }

    // ---- main loop, unroll-2 so gtA/gtB indexing is static ----
    for (int it = 0; it < NIT; it += 2) {
        // even sub-iter: A in buf 0
        if (it + 2 < NIT) load_gt(it + 2, gtB);      // depth-2 prefetch
        mfma_iter(0, it);
        if (it + 1 < NIT) convert_store(1, it + 1, gtA);
        __syncthreads();

        // odd sub-iter: A in buf 1
        if (it + 3 < NIT) load_gt(it + 3, gtA);
        mfma_iter(1, it + 1);
        if (it + 2 < NIT) convert_store(0, it + 2, gtB);
        __syncthreads();
    }

    // ---- per-row reductions (rowcnt, t2row) ----
    rcS[tid] = (float)rci;
    t2S[tid] = t2;
    __syncthreads();
    if (tid < MT) {
        rowcnt[tid] = rcS[tid*4] + rcS[tid*4+1] + rcS[tid*4+2] + rcS[tid*4+3];
        t2row[tid]  = t2S[tid*4] + t2S[tid*4+1] + t2S[tid*4+2] + t2S[tid*4+3];
    }
    __syncthreads();

    // ---- epilogue: read features once, fold all three terms ----
    float part = 0.f;
    #pragma unroll
    for (int mt = 0; mt < 4; mt++) {
        #pragma unroll
        for (int nt = 0; nt < 4; nt++) {
            const int n = w * 64 + nt * 16 + ml;
            #pragma unroll
            for (int reg = 0; reg < 4; reg++) {
                const int ri = mt * 16 + quad * 4 + reg;
                const float f = features[(size_t)(m0 + ri) * FEAT + n];
                const float T = acc[mt][nt][reg];
                part += f * (rowcnt[ri] * f - 2.f * T) + t2row[ri] * (1.f / 256.f);
            }
        }
    }
    #pragma unroll
    for (int off = 32; off > 0; off >>= 1) part += __shfl_down(part, off);
    if (lane == 0) blockred[w] = part;
    __syncthreads();
    if (tid == 0)
        atomicAdd(out, (blockred[0] + blockred[1] + blockred[2] + blockred[3]) *
                           (1.f / (float)N_ROWS));
}

extern "C" void kernel_launch(void* const* d_in, const int* in_sizes, int n_in,
                              void* d_out, int out_size, void* d_ws, size_t ws_size,
                              hipStream_t stream) {
    const int*   gt       = (const int*)d_in[0];
    const float* features = (const float*)d_in[1];
    const float* centers  = (const float*)d_in[2];
    float*       out      = (float*)d_out;

    ushort* Bfrag = (ushort*)d_ws;                                    // 256*1024*2 = 512 KB
    float*  csq   = (float*)((char*)d_ws + (size_t)FEAT * KPAD * 2);  // 4 KB

    prep_kernel<<<KPAD, 256, 0, stream>>>(centers, Bfrag, csq, out);
    main_kernel<<<N_ROWS / MT, 256, 0, stream>>>(gt, features, Bfrag, csq, out);
}